// Round 16
// baseline (88.399 us; speedup 1.0000x reference)
//
#include <hip/hip_runtime.h>
#include <hip/hip_bf16.h>
#include <math.h>

#define N_NODES 50000
#define N_EDGES 800000
#define N_FEAT 128
#define HIDDEN 16
#define N_CLASSES 16

#define NBUCK 782          // ceil(50000 / 64) buckets of 64 dst nodes
#define PB_NB 782          // partition chunks == grid (1 block/CU-sched unit)
#define PB_E  1024         // edges per partition chunk (782*1024 >= 800000)
#define BCAP  1600         // padded slots per bucket (mean 1023, sd ~32)

typedef __attribute__((ext_vector_type(8))) short short8v;     // 8 bf16 (4 VGPR)
typedef __attribute__((ext_vector_type(4))) float floatx4;     // MFMA acc
typedef __attribute__((ext_vector_type(2))) _Float16 half2v;   // fdot2 operand
typedef __attribute__((ext_vector_type(2))) __fp16 fp16x2;     // cvt_pkrtz result

__device__ __forceinline__ unsigned int f2bf_bits(float f) {
    __hip_bfloat16 h = __float2bfloat16(f);
    return (unsigned int)*reinterpret_cast<unsigned short*>(&h);
}
__device__ __forceinline__ half2v cvt_pk(float a, float b) {
    union { fp16x2 f; half2v h; } x;
    x.f = __builtin_amdgcn_cvt_pkrtz(a, b);
    return x.h;
}
__device__ __forceinline__ half2v uint_as_h2(unsigned int v) {
    union { unsigned int u; half2v h; } x; x.u = v; return x.h;
}
__device__ __forceinline__ unsigned int h2_as_uint(half2v h) {
    union { half2v h; unsigned int u; } x; x.h = h; return x.u;
}

// Edge payload (4B): bits 0-15 src, 16-21 dst_local, 22-31 u (10-bit fixed).

// ---------------------------------------------------------------------------
// Kernel A: node1 (MFMA [Nx128]@[128x48]) + bucket partition, both spread
// over ALL 782 blocks (R15 ran the partition on 196 blocks -> <1 block/CU;
// the latency-heavy scatter had no TLP and formed the kernel's tail).
// ---------------------------------------------------------------------------
__global__ __launch_bounds__(256) void k_npart(
    const float* __restrict__ x, const float* __restrict__ w1,
    const float* __restrict__ root1, const float* __restrict__ b1,
    unsigned int* __restrict__ ABu, float* __restrict__ C,
    const int* __restrict__ src, const int* __restrict__ dst,
    const float* __restrict__ u, int* __restrict__ rank,
    unsigned int* __restrict__ epr)
{
    // ---- node1 phase ----
    {
        int lane = threadIdx.x & 63;
        int wid  = threadIdx.x >> 6;
        int m = lane & 15;
        int q = lane >> 4;
        int nb = blockIdx.x * 64 + wid * 16;

        short8v bf[3][4];
#pragma unroll
        for (int c = 0; c < 4; ++c) {
            int k0 = c * 32 + q * 8;
            const float* p0 = w1 + (size_t)k0 * 16 + m;
            const float* p1 = w1 + 2048 + (size_t)k0 * 16 + m;
            const float* p2 = root1 + (size_t)k0 * 16 + m;
#pragma unroll
            for (int j = 0; j < 8; ++j) {
                bf[0][c][j] = (short)f2bf_bits(p0[j * 16]);
                bf[1][c][j] = (short)f2bf_bits(p1[j * 16]);
                bf[2][c][j] = (short)f2bf_bits(p2[j * 16]);
            }
        }

        int row = min(nb + m, N_NODES - 1);
        const float* xr = x + (size_t)row * N_FEAT;
        short8v af[4];
#pragma unroll
        for (int c = 0; c < 4; ++c) {
            int k0 = c * 32 + q * 8;
            float4 v0 = *(const float4*)(xr + k0);
            float4 v1 = *(const float4*)(xr + k0 + 4);
            af[c][0] = (short)f2bf_bits(v0.x); af[c][1] = (short)f2bf_bits(v0.y);
            af[c][2] = (short)f2bf_bits(v0.z); af[c][3] = (short)f2bf_bits(v0.w);
            af[c][4] = (short)f2bf_bits(v1.x); af[c][5] = (short)f2bf_bits(v1.y);
            af[c][6] = (short)f2bf_bits(v1.z); af[c][7] = (short)f2bf_bits(v1.w);
        }

        floatx4 acc0 = {0.f, 0.f, 0.f, 0.f};
        floatx4 acc1 = {0.f, 0.f, 0.f, 0.f};
        floatx4 acc2 = {0.f, 0.f, 0.f, 0.f};
#pragma unroll
        for (int c = 0; c < 4; ++c) {
            acc0 = __builtin_amdgcn_mfma_f32_16x16x32_bf16(af[c], bf[0][c], acc0, 0, 0, 0);
            acc1 = __builtin_amdgcn_mfma_f32_16x16x32_bf16(af[c], bf[1][c], acc1, 0, 0, 0);
            acc2 = __builtin_amdgcn_mfma_f32_16x16x32_bf16(af[c], bf[2][c], acc2, 0, 0, 0);
        }

        float bo = b1[m];
#pragma unroll
        for (int j = 0; j < 4; ++j) {
            int n = nb + q * 4 + j;
            if (n < N_NODES) {
                ABu[(size_t)n * 16 + m] = h2_as_uint(cvt_pk(acc0[j], acc1[j]));
                C[(size_t)n * 16 + m] = acc2[j] + bo;
            }
        }
    }

    // ---- partition phase (all blocks, 1024 edges each) ----
    __shared__ int cnt[NBUCK];
    for (int i = threadIdx.x; i < NBUCK; i += 256) cnt[i] = 0;
    __syncthreads();
    int ebase = blockIdx.x * PB_E;
    int myd[PB_E / 256];
#pragma unroll
    for (int k = 0; k < PB_E / 256; ++k) {
        int e = ebase + k * 256 + threadIdx.x;
        myd[k] = (e < N_EDGES) ? dst[e] : -1;
        if (myd[k] >= 0) atomicAdd(&cnt[myd[k] >> 6], 1);
    }
    __syncthreads();
    for (int i = threadIdx.x; i < NBUCK; i += 256) {
        int c = cnt[i];
        int base = (c > 0) ? atomicAdd(&rank[i], c) : 0;
        cnt[i] = i * BCAP + base;
    }
    __syncthreads();
#pragma unroll
    for (int k = 0; k < PB_E / 256; ++k) {
        if (myd[k] >= 0) {
            int e = ebase + k * 256 + threadIdx.x;
            int b = myd[k] >> 6;
            int pos = atomicAdd(&cnt[b], 1);
            unsigned int u10 = (unsigned int)(u[e] * 1023.f + 0.5f);
            if (pos < (b + 1) * BCAP)
                epr[pos] = ((unsigned int)src[e] & 0xFFFFu)
                         | (((unsigned int)myd[k] & 63u) << 16)
                         | (u10 << 22);
        }
    }
}

// ---------------------------------------------------------------------------
// Kernel B: per-bucket {counting sort in LDS -> gather1+node2 from LDS edges}.
// 1024 threads = 16 waves; wave w handles nodes 4w..4w+3 of the bucket.
// Side-effect: writes sorted epc + rowpack for gather2.
// ---------------------------------------------------------------------------
__global__ __launch_bounds__(1024) void k_sgather(
    const int* __restrict__ rank, const unsigned int* __restrict__ epr,
    unsigned int* __restrict__ epc, unsigned int* __restrict__ rowpack,
    const unsigned int* __restrict__ ABu, const float* __restrict__ C,
    const float* __restrict__ w2, const float* __restrict__ root2,
    const float* __restrict__ b2,
    unsigned int* __restrict__ ABu2, float* __restrict__ C2)
{
    __shared__ unsigned int buf[BCAP];
    __shared__ unsigned int sorted[BCAP];
    __shared__ int cnt[64], pre[64], cur[64], degl[64];
    __shared__ float W2s[16 * 48];

    int t = threadIdx.x;
    for (int i = t; i < 16 * 48; i += 1024) {
        int j = i / 48, o = i % 48;
        float v;
        if (o < 16)       v = w2[j * 16 + o];
        else if (o < 32)  v = w2[256 + j * 16 + (o - 16)];
        else              v = root2[j * 16 + (o - 32)];
        W2s[i] = v;
    }
    int b = blockIdx.x;
    int beg = b * BCAP;
    int m = min(rank[b], BCAP);
    if (t < 64) cnt[t] = 0;
    __syncthreads();

    for (int i = t; i < m; i += 1024) {
        unsigned int p = epr[beg + i];
        buf[i] = p;
        atomicAdd(&cnt[(p >> 16) & 63], 1);
    }
    __syncthreads();
    if (t < 64) {   // wave 0: 64-wide inclusive scan
        int v = cnt[t];
        int s = v;
#pragma unroll
        for (int off = 1; off < 64; off <<= 1) {
            int w = __shfl_up(s, off);
            if (t >= off) s += w;
        }
        int ex = s - v;
        pre[t] = ex;
        cur[t] = ex;
        degl[t] = v;
        int n = (b << 6) + t;
        if (n < N_NODES)
            rowpack[n] = (unsigned int)(beg + ex) | ((unsigned int)v << 21);
    }
    __syncthreads();
    for (int i = t; i < m; i += 1024) {
        unsigned int p = buf[i];
        int pos = atomicAdd(&cur[(p >> 16) & 63], 1);
        sorted[pos] = p;
    }
    __syncthreads();
    for (int i = t; i < m; i += 1024)
        epc[beg + i] = sorted[i];

    // ---- gather1 + node2 from LDS-sorted edges ----
    int wv = t >> 6;         // 0..15
    int lane = t & 63;
    int g = lane >> 3;
    int l = lane & 7;
    const uint2* AB2 = (const uint2*)ABu;
    const float uscale = 1.f / 1023.f;

#pragma unroll
    for (int j = 0; j < 4; ++j) {
        int nl = wv * 4 + j;          // 0..63
        int n = (b << 6) + nl;
        if (n >= N_NODES) break;
        int begL = pre[nl];
        int deg  = degl[nl];
        int endL = begL + deg;
        float ax = 0.f, ay = 0.f;
        int e = begL + g;
        for (; e + 8 < endL; e += 16) {
            unsigned int p0 = sorted[e];
            unsigned int p1 = sorted[e + 8];
            float u0 = (float)(p0 >> 22) * uscale;
            float u1 = (float)(p1 >> 22) * uscale;
            half2v w0 = cvt_pk(1.f - u0, u0);
            half2v w1v = cvt_pk(1.f - u1, u1);
            uint2 q0 = AB2[(size_t)(p0 & 0xFFFF) * 8 + l];
            uint2 q1 = AB2[(size_t)(p1 & 0xFFFF) * 8 + l];
            ax = __builtin_amdgcn_fdot2(w0, uint_as_h2(q0.x), ax, false);
            ay = __builtin_amdgcn_fdot2(w0, uint_as_h2(q0.y), ay, false);
            ax = __builtin_amdgcn_fdot2(w1v, uint_as_h2(q1.x), ax, false);
            ay = __builtin_amdgcn_fdot2(w1v, uint_as_h2(q1.y), ay, false);
        }
        if (e < endL) {
            unsigned int p0 = sorted[e];
            float u0 = (float)(p0 >> 22) * uscale;
            half2v w0 = cvt_pk(1.f - u0, u0);
            uint2 q0 = AB2[(size_t)(p0 & 0xFFFF) * 8 + l];
            ax = __builtin_amdgcn_fdot2(w0, uint_as_h2(q0.x), ax, false);
            ay = __builtin_amdgcn_fdot2(w0, uint_as_h2(q0.y), ay, false);
        }
#pragma unroll
        for (int s = 8; s < 64; s <<= 1) {
            ax += __shfl_xor(ax, s);
            ay += __shfl_xor(ay, s);
        }
        float dv = fmaxf((float)deg, 1.f);
        float2 cv = *(const float2*)&C[(size_t)n * 16 + 2 * l];
        float pre0 = ax / dv + cv.x;
        float pre1 = ay / dv + cv.y;
        float h0 = pre0 > 0.f ? pre0 : expm1f(pre0);
        float h1 = pre1 > 0.f ? pre1 : expm1f(pre1);

        int oc = (lane < 48) ? lane : 0;
        float val = 0.f;
#pragma unroll
        for (int j2 = 0; j2 < 8; ++j2) {
            float hh0 = __shfl(h0, j2);
            float hh1 = __shfl(h1, j2);
            val += hh0 * W2s[(2 * j2) * 48 + oc] + hh1 * W2s[(2 * j2 + 1) * 48 + oc];
        }
        float bval = __shfl(val, (lane + 16) & 63);
        if (lane < 16)
            ABu2[(size_t)n * 16 + lane] = h2_as_uint(cvt_pk(val, bval));
        else if (lane >= 32 && lane < 48)
            C2[(size_t)n * 16 + (lane - 32)] = val + b2[lane - 32];
    }
}

// ---------------------------------------------------------------------------
// Gather-mean (layer 2, fp16 dot2) + fused log_softmax -> d_out.
// ---------------------------------------------------------------------------
__global__ __launch_bounds__(256) void k_gather2(
    const unsigned int* __restrict__ rowpack, const unsigned int* __restrict__ ep,
    const unsigned int* __restrict__ ABu, const float* __restrict__ C,
    float* __restrict__ out)
{
    int n    = (blockIdx.x * 256 + threadIdx.x) >> 6;
    int lane = threadIdx.x & 63;
    int g = lane >> 3;
    int l = lane & 7;
    unsigned int rp = rowpack[n];
    int beg = (int)(rp & 0x1FFFFFu);
    int deg = (int)(rp >> 21);
    int end = beg + deg;
    const uint2* AB2 = (const uint2*)ABu;
    const float uscale = 1.f / 1023.f;
    float ax = 0.f, ay = 0.f;
    int e = beg + g;
    for (; e + 8 < end; e += 16) {
        unsigned int p0 = ep[e];
        unsigned int p1 = ep[e + 8];
        float u0 = (float)(p0 >> 22) * uscale;
        float u1 = (float)(p1 >> 22) * uscale;
        half2v w0 = cvt_pk(1.f - u0, u0);
        half2v w1v = cvt_pk(1.f - u1, u1);
        uint2 q0 = AB2[(size_t)(p0 & 0xFFFF) * 8 + l];
        uint2 q1 = AB2[(size_t)(p1 & 0xFFFF) * 8 + l];
        ax = __builtin_amdgcn_fdot2(w0, uint_as_h2(q0.x), ax, false);
        ay = __builtin_amdgcn_fdot2(w0, uint_as_h2(q0.y), ay, false);
        ax = __builtin_amdgcn_fdot2(w1v, uint_as_h2(q1.x), ax, false);
        ay = __builtin_amdgcn_fdot2(w1v, uint_as_h2(q1.y), ay, false);
    }
    if (e < end) {
        unsigned int p0 = ep[e];
        float u0 = (float)(p0 >> 22) * uscale;
        half2v w0 = cvt_pk(1.f - u0, u0);
        uint2 q0 = AB2[(size_t)(p0 & 0xFFFF) * 8 + l];
        ax = __builtin_amdgcn_fdot2(w0, uint_as_h2(q0.x), ax, false);
        ay = __builtin_amdgcn_fdot2(w0, uint_as_h2(q0.y), ay, false);
    }
#pragma unroll
    for (int s = 8; s < 64; s <<= 1) {
        ax += __shfl_xor(ax, s);
        ay += __shfl_xor(ay, s);
    }
    float dv = fmaxf((float)deg, 1.f);
    float2 cv = *(const float2*)&C[(size_t)n * 16 + 2 * l];
    float v0 = ax / dv + cv.x;
    float v1 = ay / dv + cv.y;

    float m = fmaxf(v0, v1);
#pragma unroll
    for (int s = 1; s < 8; s <<= 1) m = fmaxf(m, __shfl_xor(m, s));
    float ssum = __expf(v0 - m) + __expf(v1 - m);
#pragma unroll
    for (int s = 1; s < 8; s <<= 1) ssum += __shfl_xor(ssum, s);
    float lse = m + __logf(ssum);
    if (lane < 8)
        *(float2*)&out[(size_t)n * 16 + 2 * l] = make_float2(v0 - lse, v1 - lse);
}

extern "C" void kernel_launch(void* const* d_in, const int* in_sizes, int n_in,
                              void* d_out, int out_size, void* d_ws, size_t ws_size,
                              hipStream_t stream) {
    const float* x     = (const float*)d_in[0];
    const int*   ei    = (const int*)d_in[1];
    const float* ea    = (const float*)d_in[2];
    const float* w1    = (const float*)d_in[3];
    const float* root1 = (const float*)d_in[4];
    const float* b1    = (const float*)d_in[5];
    const float* w2    = (const float*)d_in[6];
    const float* root2 = (const float*)d_in[7];
    const float* b2    = (const float*)d_in[8];
    float* out = (float*)d_out;

    char* ws = (char*)d_ws;
    unsigned int* ABu  = (unsigned int*)ws;                         // N*16 (half2 pairs, layer 1)
    unsigned int* ABu2 = ABu + (size_t)N_NODES * 16;                // N*16 (layer 2)
    float* C    = (float*)(ABu2 + (size_t)N_NODES * 16);            // N*16 (p1)
    float* C2   = C + (size_t)N_NODES * 16;                         // N*16 (p2)
    unsigned int* EPR = (unsigned int*)(C2 + (size_t)N_NODES * 16); // NBUCK*BCAP raw 4B
    unsigned int* EPC = EPR + (size_t)NBUCK * BCAP;                 // NBUCK*BCAP sorted 4B
    int* RANK   = (int*)(EPC + (size_t)NBUCK * BCAP);               // NBUCK
    unsigned int* ROWPACK = (unsigned int*)(RANK + NBUCK);          // N

    const int* srcp = ei;
    const int* dstp = ei + N_EDGES;

    hipMemsetAsync(RANK, 0, NBUCK * sizeof(int), stream);

    k_npart<<<782, 256, 0, stream>>>(x, w1, root1, b1, ABu, C,
                                     srcp, dstp, ea, RANK, EPR);
    k_sgather<<<NBUCK, 1024, 0, stream>>>(RANK, EPR, EPC, ROWPACK, ABu, C,
                                          w2, root2, b2, ABu2, C2);
    k_gather2<<<N_NODES / 4, 256, 0, stream>>>(ROWPACK, EPC, ABu2, C2, out);
}

// Round 17
// 79.521 us; speedup vs baseline: 1.1116x; 1.1116x over previous
//
#include <hip/hip_runtime.h>
#include <hip/hip_bf16.h>
#include <math.h>

#define N_NODES 50000
#define N_EDGES 800000
#define N_FEAT 128
#define HIDDEN 16
#define N_CLASSES 16

#define NBUCK 782          // ceil(50000 / 64) buckets of 64 dst nodes
#define PB_NB 196          // partition chunks (R15 config; R16's 782 regressed)
#define PB_E  4096         // edges per partition chunk
#define BCAP  1600         // padded slots per bucket (mean 1023, sd ~32)
#define GRID_A (PB_NB + 782)   // 196 partition blocks + 782 node1 blocks

typedef __attribute__((ext_vector_type(8))) short short8v;     // 8 bf16 (4 VGPR)
typedef __attribute__((ext_vector_type(4))) float floatx4;     // MFMA acc
typedef __attribute__((ext_vector_type(2))) _Float16 half2v;   // fdot2 operand
typedef __attribute__((ext_vector_type(2))) __fp16 fp16x2;     // cvt_pkrtz result

__device__ __forceinline__ unsigned int f2bf_bits(float f) {
    __hip_bfloat16 h = __float2bfloat16(f);
    return (unsigned int)*reinterpret_cast<unsigned short*>(&h);
}
__device__ __forceinline__ half2v cvt_pk(float a, float b) {
    union { fp16x2 f; half2v h; } x;
    x.f = __builtin_amdgcn_cvt_pkrtz(a, b);
    return x.h;
}
__device__ __forceinline__ half2v uint_as_h2(unsigned int v) {
    union { unsigned int u; half2v h; } x; x.u = v; return x.h;
}
__device__ __forceinline__ unsigned int h2_as_uint(half2v h) {
    union { half2v h; unsigned int u; } x; x.h = h; return x.u;
}

// Edge payload (4B): bits 0-15 src, 16-21 dst_local, 22-31 u (10-bit fixed).

// ---------------------------------------------------------------------------
// Kernel A with DISJOINT block roles: blocks 0..195 run the bucket partition
// (latency-bound: starts at t=0, overlaps the MFMA wavefront); blocks
// 196..977 run node1 (MFMA [Nx128]@[128x48]). In R15 partition blocks did
// node1 first -> partition ran AFTER the MFMA phase at ~3 waves/CU.
// ---------------------------------------------------------------------------
__global__ __launch_bounds__(256) void k_mix(
    const float* __restrict__ x, const float* __restrict__ w1,
    const float* __restrict__ root1, const float* __restrict__ b1,
    unsigned int* __restrict__ ABu, float* __restrict__ C,
    const int* __restrict__ src, const int* __restrict__ dst,
    const float* __restrict__ u, int* __restrict__ rank,
    unsigned int* __restrict__ epr)
{
    if (blockIdx.x < PB_NB) {
        // ---- partition role ----
        __shared__ int cnt[NBUCK];
        for (int i = threadIdx.x; i < NBUCK; i += 256) cnt[i] = 0;
        __syncthreads();
        int ebase = blockIdx.x * PB_E;
        int myd[PB_E / 256];
#pragma unroll
        for (int k = 0; k < PB_E / 256; ++k) {
            int e = ebase + k * 256 + threadIdx.x;
            myd[k] = (e < N_EDGES) ? dst[e] : -1;
            if (myd[k] >= 0) atomicAdd(&cnt[myd[k] >> 6], 1);
        }
        __syncthreads();
        for (int i = threadIdx.x; i < NBUCK; i += 256) {
            int c = cnt[i];
            int base = (c > 0) ? atomicAdd(&rank[i], c) : 0;
            cnt[i] = i * BCAP + base;
        }
        __syncthreads();
#pragma unroll
        for (int k = 0; k < PB_E / 256; ++k) {
            if (myd[k] >= 0) {
                int e = ebase + k * 256 + threadIdx.x;
                int b = myd[k] >> 6;
                int pos = atomicAdd(&cnt[b], 1);
                unsigned int u10 = (unsigned int)(u[e] * 1023.f + 0.5f);
                if (pos < (b + 1) * BCAP)
                    epr[pos] = ((unsigned int)src[e] & 0xFFFFu)
                             | (((unsigned int)myd[k] & 63u) << 16)
                             | (u10 << 22);
            }
        }
        return;
    }

    // ---- node1 role ----
    int blk = blockIdx.x - PB_NB;   // 0..781
    int lane = threadIdx.x & 63;
    int wid  = threadIdx.x >> 6;
    int m = lane & 15;
    int q = lane >> 4;
    int nb = blk * 64 + wid * 16;

    short8v bf[3][4];
#pragma unroll
    for (int c = 0; c < 4; ++c) {
        int k0 = c * 32 + q * 8;
        const float* p0 = w1 + (size_t)k0 * 16 + m;
        const float* p1 = w1 + 2048 + (size_t)k0 * 16 + m;
        const float* p2 = root1 + (size_t)k0 * 16 + m;
#pragma unroll
        for (int j = 0; j < 8; ++j) {
            bf[0][c][j] = (short)f2bf_bits(p0[j * 16]);
            bf[1][c][j] = (short)f2bf_bits(p1[j * 16]);
            bf[2][c][j] = (short)f2bf_bits(p2[j * 16]);
        }
    }

    int row = min(nb + m, N_NODES - 1);
    const float* xr = x + (size_t)row * N_FEAT;
    short8v af[4];
#pragma unroll
    for (int c = 0; c < 4; ++c) {
        int k0 = c * 32 + q * 8;
        float4 v0 = *(const float4*)(xr + k0);
        float4 v1 = *(const float4*)(xr + k0 + 4);
        af[c][0] = (short)f2bf_bits(v0.x); af[c][1] = (short)f2bf_bits(v0.y);
        af[c][2] = (short)f2bf_bits(v0.z); af[c][3] = (short)f2bf_bits(v0.w);
        af[c][4] = (short)f2bf_bits(v1.x); af[c][5] = (short)f2bf_bits(v1.y);
        af[c][6] = (short)f2bf_bits(v1.z); af[c][7] = (short)f2bf_bits(v1.w);
    }

    floatx4 acc0 = {0.f, 0.f, 0.f, 0.f};
    floatx4 acc1 = {0.f, 0.f, 0.f, 0.f};
    floatx4 acc2 = {0.f, 0.f, 0.f, 0.f};
#pragma unroll
    for (int c = 0; c < 4; ++c) {
        acc0 = __builtin_amdgcn_mfma_f32_16x16x32_bf16(af[c], bf[0][c], acc0, 0, 0, 0);
        acc1 = __builtin_amdgcn_mfma_f32_16x16x32_bf16(af[c], bf[1][c], acc1, 0, 0, 0);
        acc2 = __builtin_amdgcn_mfma_f32_16x16x32_bf16(af[c], bf[2][c], acc2, 0, 0, 0);
    }

    float bo = b1[m];
#pragma unroll
    for (int j = 0; j < 4; ++j) {
        int n = nb + q * 4 + j;
        if (n < N_NODES) {
            ABu[(size_t)n * 16 + m] = h2_as_uint(cvt_pk(acc0[j], acc1[j]));
            C[(size_t)n * 16 + m] = acc2[j] + bo;
        }
    }
}

// ---------------------------------------------------------------------------
// Kernel B: per-bucket {counting sort in LDS -> gather1+node2 from LDS edges}.
// 1024 threads = 16 waves; wave w handles nodes 4w..4w+3 of the bucket.
// Side-effect: writes sorted epc + rowpack for gather2.
// ---------------------------------------------------------------------------
__global__ __launch_bounds__(1024) void k_sgather(
    const int* __restrict__ rank, const unsigned int* __restrict__ epr,
    unsigned int* __restrict__ epc, unsigned int* __restrict__ rowpack,
    const unsigned int* __restrict__ ABu, const float* __restrict__ C,
    const float* __restrict__ w2, const float* __restrict__ root2,
    const float* __restrict__ b2,
    unsigned int* __restrict__ ABu2, float* __restrict__ C2)
{
    __shared__ unsigned int buf[BCAP];
    __shared__ unsigned int sorted[BCAP];
    __shared__ int cnt[64], pre[64], cur[64], degl[64];
    __shared__ float W2s[16 * 48];

    int t = threadIdx.x;
    for (int i = t; i < 16 * 48; i += 1024) {
        int j = i / 48, o = i % 48;
        float v;
        if (o < 16)       v = w2[j * 16 + o];
        else if (o < 32)  v = w2[256 + j * 16 + (o - 16)];
        else              v = root2[j * 16 + (o - 32)];
        W2s[i] = v;
    }
    int b = blockIdx.x;
    int beg = b * BCAP;
    int m = min(rank[b], BCAP);
    if (t < 64) cnt[t] = 0;
    __syncthreads();

    for (int i = t; i < m; i += 1024) {
        unsigned int p = epr[beg + i];
        buf[i] = p;
        atomicAdd(&cnt[(p >> 16) & 63], 1);
    }
    __syncthreads();
    if (t < 64) {   // wave 0: 64-wide inclusive scan
        int v = cnt[t];
        int s = v;
#pragma unroll
        for (int off = 1; off < 64; off <<= 1) {
            int w = __shfl_up(s, off);
            if (t >= off) s += w;
        }
        int ex = s - v;
        pre[t] = ex;
        cur[t] = ex;
        degl[t] = v;
        int n = (b << 6) + t;
        if (n < N_NODES)
            rowpack[n] = (unsigned int)(beg + ex) | ((unsigned int)v << 21);
    }
    __syncthreads();
    for (int i = t; i < m; i += 1024) {
        unsigned int p = buf[i];
        int pos = atomicAdd(&cur[(p >> 16) & 63], 1);
        sorted[pos] = p;
    }
    __syncthreads();
    for (int i = t; i < m; i += 1024)
        epc[beg + i] = sorted[i];

    // ---- gather1 + node2 from LDS-sorted edges ----
    int wv = t >> 6;         // 0..15
    int lane = t & 63;
    int g = lane >> 3;
    int l = lane & 7;
    const uint2* AB2 = (const uint2*)ABu;
    const float uscale = 1.f / 1023.f;

#pragma unroll
    for (int j = 0; j < 4; ++j) {
        int nl = wv * 4 + j;          // 0..63
        int n = (b << 6) + nl;
        if (n >= N_NODES) break;
        int begL = pre[nl];
        int deg  = degl[nl];
        int endL = begL + deg;
        float ax = 0.f, ay = 0.f;
        int e = begL + g;
        for (; e + 8 < endL; e += 16) {
            unsigned int p0 = sorted[e];
            unsigned int p1 = sorted[e + 8];
            float u0 = (float)(p0 >> 22) * uscale;
            float u1 = (float)(p1 >> 22) * uscale;
            half2v w0 = cvt_pk(1.f - u0, u0);
            half2v w1v = cvt_pk(1.f - u1, u1);
            uint2 q0 = AB2[(size_t)(p0 & 0xFFFF) * 8 + l];
            uint2 q1 = AB2[(size_t)(p1 & 0xFFFF) * 8 + l];
            ax = __builtin_amdgcn_fdot2(w0, uint_as_h2(q0.x), ax, false);
            ay = __builtin_amdgcn_fdot2(w0, uint_as_h2(q0.y), ay, false);
            ax = __builtin_amdgcn_fdot2(w1v, uint_as_h2(q1.x), ax, false);
            ay = __builtin_amdgcn_fdot2(w1v, uint_as_h2(q1.y), ay, false);
        }
        if (e < endL) {
            unsigned int p0 = sorted[e];
            float u0 = (float)(p0 >> 22) * uscale;
            half2v w0 = cvt_pk(1.f - u0, u0);
            uint2 q0 = AB2[(size_t)(p0 & 0xFFFF) * 8 + l];
            ax = __builtin_amdgcn_fdot2(w0, uint_as_h2(q0.x), ax, false);
            ay = __builtin_amdgcn_fdot2(w0, uint_as_h2(q0.y), ay, false);
        }
#pragma unroll
        for (int s = 8; s < 64; s <<= 1) {
            ax += __shfl_xor(ax, s);
            ay += __shfl_xor(ay, s);
        }
        float dv = fmaxf((float)deg, 1.f);
        float2 cv = *(const float2*)&C[(size_t)n * 16 + 2 * l];
        float pre0 = ax / dv + cv.x;
        float pre1 = ay / dv + cv.y;
        float h0 = pre0 > 0.f ? pre0 : expm1f(pre0);
        float h1 = pre1 > 0.f ? pre1 : expm1f(pre1);

        int oc = (lane < 48) ? lane : 0;
        float val = 0.f;
#pragma unroll
        for (int j2 = 0; j2 < 8; ++j2) {
            float hh0 = __shfl(h0, j2);
            float hh1 = __shfl(h1, j2);
            val += hh0 * W2s[(2 * j2) * 48 + oc] + hh1 * W2s[(2 * j2 + 1) * 48 + oc];
        }
        float bval = __shfl(val, (lane + 16) & 63);
        if (lane < 16)
            ABu2[(size_t)n * 16 + lane] = h2_as_uint(cvt_pk(val, bval));
        else if (lane >= 32 && lane < 48)
            C2[(size_t)n * 16 + (lane - 32)] = val + b2[lane - 32];
    }
}

// ---------------------------------------------------------------------------
// Gather-mean (layer 2, fp16 dot2) + fused log_softmax -> d_out.
// ---------------------------------------------------------------------------
__global__ __launch_bounds__(256) void k_gather2(
    const unsigned int* __restrict__ rowpack, const unsigned int* __restrict__ ep,
    const unsigned int* __restrict__ ABu, const float* __restrict__ C,
    float* __restrict__ out)
{
    int n    = (blockIdx.x * 256 + threadIdx.x) >> 6;
    int lane = threadIdx.x & 63;
    int g = lane >> 3;
    int l = lane & 7;
    unsigned int rp = rowpack[n];
    int beg = (int)(rp & 0x1FFFFFu);
    int deg = (int)(rp >> 21);
    int end = beg + deg;
    const uint2* AB2 = (const uint2*)ABu;
    const float uscale = 1.f / 1023.f;
    float ax = 0.f, ay = 0.f;
    int e = beg + g;
    for (; e + 8 < end; e += 16) {
        unsigned int p0 = ep[e];
        unsigned int p1 = ep[e + 8];
        float u0 = (float)(p0 >> 22) * uscale;
        float u1 = (float)(p1 >> 22) * uscale;
        half2v w0 = cvt_pk(1.f - u0, u0);
        half2v w1v = cvt_pk(1.f - u1, u1);
        uint2 q0 = AB2[(size_t)(p0 & 0xFFFF) * 8 + l];
        uint2 q1 = AB2[(size_t)(p1 & 0xFFFF) * 8 + l];
        ax = __builtin_amdgcn_fdot2(w0, uint_as_h2(q0.x), ax, false);
        ay = __builtin_amdgcn_fdot2(w0, uint_as_h2(q0.y), ay, false);
        ax = __builtin_amdgcn_fdot2(w1v, uint_as_h2(q1.x), ax, false);
        ay = __builtin_amdgcn_fdot2(w1v, uint_as_h2(q1.y), ay, false);
    }
    if (e < end) {
        unsigned int p0 = ep[e];
        float u0 = (float)(p0 >> 22) * uscale;
        half2v w0 = cvt_pk(1.f - u0, u0);
        uint2 q0 = AB2[(size_t)(p0 & 0xFFFF) * 8 + l];
        ax = __builtin_amdgcn_fdot2(w0, uint_as_h2(q0.x), ax, false);
        ay = __builtin_amdgcn_fdot2(w0, uint_as_h2(q0.y), ay, false);
    }
#pragma unroll
    for (int s = 8; s < 64; s <<= 1) {
        ax += __shfl_xor(ax, s);
        ay += __shfl_xor(ay, s);
    }
    float dv = fmaxf((float)deg, 1.f);
    float2 cv = *(const float2*)&C[(size_t)n * 16 + 2 * l];
    float v0 = ax / dv + cv.x;
    float v1 = ay / dv + cv.y;

    float m = fmaxf(v0, v1);
#pragma unroll
    for (int s = 1; s < 8; s <<= 1) m = fmaxf(m, __shfl_xor(m, s));
    float ssum = __expf(v0 - m) + __expf(v1 - m);
#pragma unroll
    for (int s = 1; s < 8; s <<= 1) ssum += __shfl_xor(ssum, s);
    float lse = m + __logf(ssum);
    if (lane < 8)
        *(float2*)&out[(size_t)n * 16 + 2 * l] = make_float2(v0 - lse, v1 - lse);
}

extern "C" void kernel_launch(void* const* d_in, const int* in_sizes, int n_in,
                              void* d_out, int out_size, void* d_ws, size_t ws_size,
                              hipStream_t stream) {
    const float* x     = (const float*)d_in[0];
    const int*   ei    = (const int*)d_in[1];
    const float* ea    = (const float*)d_in[2];
    const float* w1    = (const float*)d_in[3];
    const float* root1 = (const float*)d_in[4];
    const float* b1    = (const float*)d_in[5];
    const float* w2    = (const float*)d_in[6];
    const float* root2 = (const float*)d_in[7];
    const float* b2    = (const float*)d_in[8];
    float* out = (float*)d_out;

    char* ws = (char*)d_ws;
    unsigned int* ABu  = (unsigned int*)ws;                         // N*16 (half2 pairs, layer 1)
    unsigned int* ABu2 = ABu + (size_t)N_NODES * 16;                // N*16 (layer 2)
    float* C    = (float*)(ABu2 + (size_t)N_NODES * 16);            // N*16 (p1)
    float* C2   = C + (size_t)N_NODES * 16;                         // N*16 (p2)
    unsigned int* EPR = (unsigned int*)(C2 + (size_t)N_NODES * 16); // NBUCK*BCAP raw 4B
    unsigned int* EPC = EPR + (size_t)NBUCK * BCAP;                 // NBUCK*BCAP sorted 4B
    int* RANK   = (int*)(EPC + (size_t)NBUCK * BCAP);               // NBUCK
    unsigned int* ROWPACK = (unsigned int*)(RANK + NBUCK);          // N

    const int* srcp = ei;
    const int* dstp = ei + N_EDGES;

    hipMemsetAsync(RANK, 0, NBUCK * sizeof(int), stream);

    k_mix<<<GRID_A, 256, 0, stream>>>(x, w1, root1, b1, ABu, C,
                                      srcp, dstp, ea, RANK, EPR);
    k_sgather<<<NBUCK, 1024, 0, stream>>>(RANK, EPR, EPC, ROWPACK, ABu, C,
                                          w2, root2, b2, ABu2, C2);
    k_gather2<<<N_NODES / 4, 256, 0, stream>>>(ROWPACK, EPC, ABu2, C2, out);
}